// Round 3
// baseline (4209.624 us; speedup 1.0000x reference)
//
#include <hip/hip_runtime.h>

typedef _Float16 half_t;
typedef _Float16 half4 __attribute__((ext_vector_type(4)));
typedef _Float16 half8 __attribute__((ext_vector_type(8)));
typedef float floatx4 __attribute__((ext_vector_type(4)));
typedef unsigned long long ull_t;

#define SEQ 256
#define BATCH 64
#define EMB 256
#define HID 512
#define NOUT 18
#define M_TOT (SEQ*BATCH)   // 16384

// ---------------- ws layout (bytes) ----------------
// FLG: per-layer flag array [2 dir][256 step][64 wave] int = 131072 B (re-zeroed between layers)
#define O_FLG    0u
#define O_HB0    131072u     // layer0 h double buffers: [2 dir][2][64][512] half = 262144
#define O_HB1    393216u     // layer1 same
#define O_EMFC16 655360u     // 65536 half
#define O_WIH0   786432u     // 1024*256 half
#define O_WIH1   1310720u    // 1024*1024 half
#define O_FC16   3407872u    // 18*1024 half (pad region to 3444736)
#define O_XP     3444736u    // xp 16384*1024 half (shared by layer0/layer1)
#define O_OUT0   36999168u   // 16384*1024 half
#define O_OUT1   70553600u   // 16384*1024 half
#define O_PE     O_OUT1      // post_emb 16384*256 half ALIASES OUT1 (PE dead before OUT1 written)
// total 104108032 bytes (< round-2's working 112365824)

// ---------------- zero helper ----------------
__global__ void zero_ws(uint4* p, int n) {
    int i = blockIdx.x * 256 + threadIdx.x;
    if (i < n) p[i] = make_uint4(0u, 0u, 0u, 0u);
}

// ---------------- fp32 -> fp16 convert (8 elems/thread) ----------------
__global__ void cvt_f32f16(const float* __restrict__ s, half_t* __restrict__ d, int n8) {
    int i = blockIdx.x * 256 + threadIdx.x;
    if (i < n8) {
        const float4* s4 = (const float4*)s;
        float4 a = s4[2*i], b = s4[2*i+1];
        half8 h;
        h[0]=(_Float16)a.x; h[1]=(_Float16)a.y; h[2]=(_Float16)a.z; h[3]=(_Float16)a.w;
        h[4]=(_Float16)b.x; h[5]=(_Float16)b.y; h[6]=(_Float16)b.z; h[7]=(_Float16)b.w;
        *(half8*)(d + (size_t)i*8) = h;
    }
}

// ---------------- generic NT GEMM: C[m,n] = sum_k A[m,k]*B[n,k] + bias ----------------
// BM=128 BN=128 BK=32, 256 threads (4 waves 2x2), fp16 MFMA 16x16x32, fp16 out.
template<bool GATHER>
__global__ __launch_bounds__(256)
void gemm_nt(const half_t* __restrict__ A, const float* __restrict__ Atab,
             const int* __restrict__ gidx, const half_t* __restrict__ Bm,
             const float* __restrict__ bias0, const float* __restrict__ bias1,
             half_t* __restrict__ Cout, int M, int N, int K)
{
    __shared__ half8 As8[512];   // 128 x 32 half
    __shared__ half8 Bs8[512];
    half_t* As = (half_t*)As8;
    half_t* Bs = (half_t*)Bs8;

    const int tid  = threadIdx.x;
    const int lane = tid & 63, wid = tid >> 6;
    const int wm = wid >> 1, wn = wid & 1;
    const int ln = lane & 15, hi = lane >> 4;
    const int m0 = blockIdx.x * 128, n0 = blockIdx.y * 128;

    floatx4 acc[4][4] = {};
    const int kTiles = K >> 5;

    for (int kt = 0; kt < kTiles; ++kt) {
        if constexpr (GATHER) {
            int r = tid >> 1, q = tid & 1;
            int row = gidx[m0 + r];
            const float* src = Atab + (size_t)row * EMB + kt*32 + q*16;
            float4 f0 = *(const float4*)(src);
            float4 f1 = *(const float4*)(src + 4);
            float4 f2 = *(const float4*)(src + 8);
            float4 f3 = *(const float4*)(src + 12);
            half8 h0, h1;
            h0[0]=(_Float16)f0.x; h0[1]=(_Float16)f0.y; h0[2]=(_Float16)f0.z; h0[3]=(_Float16)f0.w;
            h0[4]=(_Float16)f1.x; h0[5]=(_Float16)f1.y; h0[6]=(_Float16)f1.z; h0[7]=(_Float16)f1.w;
            h1[0]=(_Float16)f2.x; h1[1]=(_Float16)f2.y; h1[2]=(_Float16)f2.z; h1[3]=(_Float16)f2.w;
            h1[4]=(_Float16)f3.x; h1[5]=(_Float16)f3.y; h1[6]=(_Float16)f3.z; h1[7]=(_Float16)f3.w;
            int c0 = 2*q, c1 = 2*q + 1;
            *(half8*)(As + r*32 + (((c0 + (r>>1)) & 3) * 8)) = h0;
            *(half8*)(As + r*32 + (((c1 + (r>>1)) & 3) * 8)) = h1;
        } else {
            #pragma unroll
            for (int ii = 0; ii < 2; ++ii) {
                int ch = tid + ii*256; int r = ch >> 2, c = ch & 3;
                half8 v = *(const half8*)(A + (size_t)(m0+r)*K + kt*32 + c*8);
                *(half8*)(As + r*32 + (((c + (r>>1)) & 3) * 8)) = v;
            }
        }
        #pragma unroll
        for (int ii = 0; ii < 2; ++ii) {
            int ch = tid + ii*256; int r = ch >> 2, c = ch & 3;
            half8 v = *(const half8*)(Bm + (size_t)(n0+r)*K + kt*32 + c*8);
            *(half8*)(Bs + r*32 + (((c + (r>>1)) & 3) * 8)) = v;
        }
        __syncthreads();

        half8 af[4], bf[4];
        #pragma unroll
        for (int mt = 0; mt < 4; ++mt) {
            int r = wm*64 + mt*16 + ln;
            af[mt] = *(const half8*)(As + r*32 + ((hi + (r>>1)) & 3) * 8);
        }
        #pragma unroll
        for (int nt = 0; nt < 4; ++nt) {
            int r = wn*64 + nt*16 + ln;
            bf[nt] = *(const half8*)(Bs + r*32 + ((hi + (r>>1)) & 3) * 8);
        }
        #pragma unroll
        for (int mt = 0; mt < 4; ++mt)
            #pragma unroll
            for (int nt = 0; nt < 4; ++nt)
                acc[mt][nt] = __builtin_amdgcn_mfma_f32_16x16x32_f16(af[mt], bf[nt], acc[mt][nt], 0, 0, 0);
        __syncthreads();
    }

    #pragma unroll
    for (int mt = 0; mt < 4; ++mt) {
        #pragma unroll
        for (int nt = 0; nt < 4; ++nt) {
            int n = n0 + wn*64 + nt*16 + ln;
            float bv = (bias0 ? bias0[n] : 0.f) + (bias1 ? bias1[n] : 0.f);
            #pragma unroll
            for (int r = 0; r < 4; ++r) {
                int m = m0 + wm*64 + mt*16 + hi*4 + r;
                Cout[(size_t)m*N + n] = (half_t)(acc[mt][nt][r] + bv);
            }
        }
    }
}

// ---------------- persistent bidirectional RNN layer (round 3) ----------------
// grid = 32 blocks x 256 thr. dir = bid>>4; j-slice = (bid&15)*32; wave w -> batches [16w,16w+16).
// D[j][b] = sum_k W[j][k] h[b][k]: A = W (registers), B = h (8B relaxed atomic loads).
// Sync: per-WAVE flag words flags[dir][step][64] (write-once per step, no RMW, no __syncthreads):
//   producer: h stores -> s_waitcnt vmcnt(0) (ONLY h outstanding) -> lane0 flag:=1
//   consumer: 64 lanes load flags[step-1][0..63], ballot-all -> proceed (tight poll, no sleep)
// outbuf stores + xp prefetch issued AFTER flag post (off critical path).
__global__ __launch_bounds__(256, 1)
void rnn_layer(const half_t* __restrict__ xp, half_t* __restrict__ outbuf,
               const float* __restrict__ whh, ull_t* __restrict__ hb,
               int* __restrict__ flg)
{
    const int bid = blockIdx.x;
    const int dir = bid >> 4;
    const int j0  = (bid & 15) * 32;
    const int wid = threadIdx.x >> 6, lane = threadIdx.x & 63;
    const int ln = lane & 15, hi = lane >> 4;
    const int b0 = wid * 16;

    // A-operand (W) fragments: afrag[mt][kk] lane holds W[j0+mt*16+ln][kk*32+hi*8 + i]
    half8 afrag[2][16];
    #pragma unroll
    for (int mt = 0; mt < 2; ++mt) {
        #pragma unroll
        for (int kk = 0; kk < 16; ++kk) {
            const float* wp = whh + ((size_t)(dir*HID + j0 + mt*16 + ln))*HID + kk*32 + hi*8;
            float4 f0 = *(const float4*)wp;
            float4 f1 = *(const float4*)(wp + 4);
            half8 h;
            h[0]=(_Float16)f0.x; h[1]=(_Float16)f0.y; h[2]=(_Float16)f0.z; h[3]=(_Float16)f0.w;
            h[4]=(_Float16)f1.x; h[5]=(_Float16)f1.y; h[6]=(_Float16)f1.z; h[7]=(_Float16)f1.w;
            afrag[mt][kk] = h;
        }
    }

    // h double buffers in ull units: [2 buf][8192 ull] per direction
    ull_t* hb_d = hb + (size_t)dir * 16384;
    int* flg_d  = flg + dir * (SEQ * 64);
    const int fidx = (bid & 15) * 4 + wid;

    // per-lane fixed offsets
    const int b    = b0 + ln;                       // batch row this lane reads/writes
    const int jb0  = j0 + hi*4;                     // j quad base, mt adds 16
    const int hrd  = b*128 + hi*2;                  // ull idx base for B-frag reads (+kk*8)
    const int hwr  = b*128 + (jb0 >> 2);            // ull idx base for h writes (+mt*4)

    // prefetch xp for step 0
    half4 xq[2];
    {
        int t0 = dir ? (SEQ-1) : 0;
        const half_t* xb = xp + ((size_t)(t0*BATCH + b))*(2*HID) + dir*HID + jb0;
        xq[0] = *(const half4*)(xb);
        xq[1] = *(const half4*)(xb + 16);
    }

    for (int step = 0; step < SEQ; ++step) {
        const int t = dir ? (SEQ-1 - step) : step;
        const ull_t* hc = hb_d + (size_t)(step & 1) * 8192;
        ull_t*       hn = hb_d + (size_t)((step+1) & 1) * 8192;

        // wait until h_step fully published: all 64 wave-flags of prior step set
        if (step) {
            const int* fp = flg_d + (step-1)*64;
            for (;;) {
                int f = __hip_atomic_load(fp + lane, __ATOMIC_RELAXED, __HIP_MEMORY_SCOPE_AGENT);
                if (__ballot(f != 0) == ~0ull) break;
            }
            asm volatile("" ::: "memory");   // no reordering of bf loads above the poll
        }

        // B-operand (h) fragments: 2 relaxed 8B atomic loads per kk (16B contiguous)
        half8 bf[16];
        #pragma unroll
        for (int kk = 0; kk < 16; ++kk) {
            const ull_t* p = hc + hrd + kk*8;
            struct U2 { ull_t a, c; } u;
            u.a = __hip_atomic_load(p,     __ATOMIC_RELAXED, __HIP_MEMORY_SCOPE_AGENT);
            u.c = __hip_atomic_load(p + 1, __ATOMIC_RELAXED, __HIP_MEMORY_SCOPE_AGENT);
            bf[kk] = __builtin_bit_cast(half8, u);
        }

        floatx4 acc0 = {0.f,0.f,0.f,0.f};
        floatx4 acc1 = {0.f,0.f,0.f,0.f};
        #pragma unroll
        for (int kk = 0; kk < 16; ++kk) {
            acc0 = __builtin_amdgcn_mfma_f32_16x16x32_f16(afrag[0][kk], bf[kk], acc0, 0, 0, 0);
            acc1 = __builtin_amdgcn_mfma_f32_16x16x32_f16(afrag[1][kk], bf[kk], acc1, 0, 0, 0);
        }

        // epilogue: v = relu(acc + xp); publish h FIRST, then flag, then cached outbuf
        half4 hv[2];
        #pragma unroll
        for (int mt = 0; mt < 2; ++mt) {
            floatx4 a = mt ? acc1 : acc0;
            #pragma unroll
            for (int r = 0; r < 4; ++r)
                hv[mt][r] = (_Float16)fmaxf(a[r] + (float)xq[mt][r], 0.f);
        }
        if (step + 1 < SEQ) {
            #pragma unroll
            for (int mt = 0; mt < 2; ++mt)
                __hip_atomic_store(hn + hwr + mt*4,
                                   __builtin_bit_cast(ull_t, hv[mt]),
                                   __ATOMIC_RELAXED, __HIP_MEMORY_SCOPE_AGENT);
            asm volatile("s_waitcnt vmcnt(0)" ::: "memory");   // h stores acked at coherence point
            if (lane == 0)
                __hip_atomic_store(flg_d + step*64 + fidx, 1,
                                   __ATOMIC_RELAXED, __HIP_MEMORY_SCOPE_AGENT);
        }

        // off-critical-path: cached output store + next-step xp prefetch
        const size_t orow = ((size_t)t*BATCH + b)*(2*HID) + dir*HID;
        #pragma unroll
        for (int mt = 0; mt < 2; ++mt)
            *(half4*)(outbuf + orow + jb0 + mt*16) = hv[mt];

        if (step + 1 < SEQ) {
            int tn = dir ? (SEQ-2 - step) : (step+1);
            const half_t* xb = xp + ((size_t)(tn*BATCH + b))*(2*HID) + dir*HID + jb0;
            xq[0] = *(const half4*)(xb);
            xq[1] = *(const half4*)(xb + 16);
        }
    }
}

// ---------------- final FC: [16384,1024] x [18,1024]^T + b ----------------
__global__ __launch_bounds__(256)
void fc_kernel(const half_t* __restrict__ X, const half_t* __restrict__ W16,
               const float* __restrict__ bias, float* __restrict__ Y)
{
    __shared__ half8 Ws8[2304];   // 18*1024 half
    half_t* Ws = (half_t*)Ws8;
    for (int ch = threadIdx.x; ch < 2304; ch += 256)
        Ws8[ch] = *(const half8*)(W16 + (size_t)ch*8);
    __syncthreads();

    int wi = threadIdx.x >> 6, lane = threadIdx.x & 63;
    int m = blockIdx.x*4 + wi;
    const half_t* xr = X + (size_t)m*1024 + lane*16;
    half8 x0 = *(const half8*)xr;
    half8 x1 = *(const half8*)(xr + 8);
    float xa[16];
    #pragma unroll
    for (int i = 0; i < 8; ++i) { xa[i] = (float)x0[i]; xa[8+i] = (float)x1[i]; }

    for (int n = 0; n < NOUT; ++n) {
        const half_t* wr = Ws + n*1024 + lane*16;
        half8 w0 = *(const half8*)wr;
        half8 w1 = *(const half8*)(wr + 8);
        float s = 0.f;
        #pragma unroll
        for (int i = 0; i < 8; ++i) s += xa[i]*(float)w0[i] + xa[8+i]*(float)w1[i];
        #pragma unroll
        for (int off = 32; off > 0; off >>= 1) s += __shfl_down(s, off, 64);
        if (lane == 0) Y[(size_t)m*NOUT + n] = s + bias[n];
    }
}

// ---------------- launcher ----------------
extern "C" void kernel_launch(void* const* d_in, const int* in_sizes, int n_in,
                              void* d_out, int out_size, void* d_ws, size_t ws_size,
                              hipStream_t stream)
{
    const int*   text    = (const int*)  d_in[0];
    const float* emb     = (const float*)d_in[1];
    const float* emfc_w  = (const float*)d_in[2];
    const float* emfc_b  = (const float*)d_in[3];
    const float* w_ih0   = (const float*)d_in[4];
    const float* w_hh0   = (const float*)d_in[5];
    const float* b_ih0   = (const float*)d_in[6];
    const float* b_hh0   = (const float*)d_in[7];
    const float* w_ih1   = (const float*)d_in[8];
    const float* w_hh1   = (const float*)d_in[9];
    const float* b_ih1   = (const float*)d_in[10];
    const float* b_hh1   = (const float*)d_in[11];
    const float* fc_w    = (const float*)d_in[12];
    const float* fc_b    = (const float*)d_in[13];
    float* out = (float*)d_out;

    char* ws = (char*)d_ws;
    int*    flg    = (int*)   (ws + O_FLG);
    ull_t*  hb0    = (ull_t*) (ws + O_HB0);
    ull_t*  hb1    = (ull_t*) (ws + O_HB1);
    half_t* emfc16 = (half_t*)(ws + O_EMFC16);
    half_t* wih0   = (half_t*)(ws + O_WIH0);
    half_t* wih1   = (half_t*)(ws + O_WIH1);
    half_t* fc16   = (half_t*)(ws + O_FC16);
    half_t* pe     = (half_t*)(ws + O_PE);
    half_t* xp     = (half_t*)(ws + O_XP);
    half_t* out0   = (half_t*)(ws + O_OUT0);
    half_t* out1   = (half_t*)(ws + O_OUT1);

    // 1) zero flags + h buffers  ([0, 655360) = 40960 uint4)
    zero_ws<<<160, 256, 0, stream>>>((uint4*)ws, 40960);

    // 2) weight conversions fp32->fp16
    cvt_f32f16<<<32,  256, 0, stream>>>(emfc_w, emfc16, 8192);
    cvt_f32f16<<<128, 256, 0, stream>>>(w_ih0,  wih0,  32768);
    cvt_f32f16<<<512, 256, 0, stream>>>(w_ih1,  wih1, 131072);
    cvt_f32f16<<<9,   256, 0, stream>>>(fc_w,   fc16,   2304);

    // 3) post_emb = gather(emb, text) @ emfc_w^T + emfc_b   (PE aliases OUT1 region)
    gemm_nt<true><<<dim3(M_TOT/128, EMB/128), 256, 0, stream>>>(
        nullptr, emb, text, emfc16, emfc_b, nullptr, pe, M_TOT, EMB, EMB);

    // 4) xp0 = post_emb @ w_ih0^T + (b_ih0 + b_hh0)
    gemm_nt<false><<<dim3(M_TOT/128, (2*HID)/128), 256, 0, stream>>>(
        pe, nullptr, nullptr, wih0, b_ih0, b_hh0, xp, M_TOT, 2*HID, EMB);

    // 5) layer0 recurrence (both directions)
    rnn_layer<<<32, 256, 0, stream>>>(xp, out0, w_hh0, hb0, flg);

    // 5b) re-zero flags for layer1 (kernel-boundary release makes zeros agent-visible)
    zero_ws<<<32, 256, 0, stream>>>((uint4*)(ws + O_FLG), 8192);

    // 6) xp1 = out0 @ w_ih1^T + (b_ih1 + b_hh1)
    gemm_nt<false><<<dim3(M_TOT/128, (2*HID)/128), 256, 0, stream>>>(
        out0, nullptr, nullptr, wih1, b_ih1, b_hh1, xp, M_TOT, 2*HID, 2*HID);

    // 7) layer1 recurrence
    rnn_layer<<<32, 256, 0, stream>>>(xp, out1, w_hh1, hb1, flg);

    // 8) out = out1 @ fc_w^T + fc_b
    fc_kernel<<<M_TOT/4, 256, 0, stream>>>(out1, fc16, fc_b, out);
}

// Round 4
// 4007.454 us; speedup vs baseline: 1.0504x; 1.0504x over previous
//
#include <hip/hip_runtime.h>

typedef _Float16 half_t;
typedef _Float16 half4 __attribute__((ext_vector_type(4)));
typedef _Float16 half8 __attribute__((ext_vector_type(8)));
typedef float floatx4 __attribute__((ext_vector_type(4)));
typedef unsigned long long ull_t;

#define SEQ 256
#define BATCH 64
#define EMB 256
#define HID 512
#define NOUT 18
#define M_TOT (SEQ*BATCH)   // 16384

// ---------------- ws layout (bytes) ----------------
// HB: per-layer h double buffers [2 dir][2 buf][64 b][512 j] fp16, sign-bit = step tag
#define O_HB0    0u          // 262144
#define O_HB1    262144u     // 262144
#define O_EMFC16 524288u     // 65536 half = 131072
#define O_WIH0   655360u     // 1024*256 half = 524288
#define O_WIH1   1179648u    // 1024*1024 half = 2097152
#define O_FC16   3276800u    // 18*1024 half = 36864
#define O_XP     3313664u    // 16384*1024 half = 33554432 (shared by layer0/layer1)
#define O_OUT0   36868096u   // 16384*1024 half
#define O_OUT1   70422528u   // 16384*1024 half
#define O_PE     O_OUT1      // post_emb 16384*256 half ALIASES OUT1 (PE dead before OUT1 written)
// total 103976960 bytes

// ---------------- init h buffers: buf0 = +0.0 (tag 0, valid h_0), buf1 = 0x8000 (tag 1 = stale) ----------------
__global__ void init_hb(uint4* p) {
    int i = blockIdx.x * 256 + threadIdx.x;        // 32768 uint4 = 524288 B
    unsigned v = ((i >> 12) & 1) ? 0x80008000u : 0u;  // 4096 uint4 per 65536-B buffer, buf index bit
    p[i] = make_uint4(v, v, v, v);
}

// ---------------- fp32 -> fp16 convert (8 elems/thread) ----------------
__global__ void cvt_f32f16(const float* __restrict__ s, half_t* __restrict__ d, int n8) {
    int i = blockIdx.x * 256 + threadIdx.x;
    if (i < n8) {
        const float4* s4 = (const float4*)s;
        float4 a = s4[2*i], b = s4[2*i+1];
        half8 h;
        h[0]=(_Float16)a.x; h[1]=(_Float16)a.y; h[2]=(_Float16)a.z; h[3]=(_Float16)a.w;
        h[4]=(_Float16)b.x; h[5]=(_Float16)b.y; h[6]=(_Float16)b.z; h[7]=(_Float16)b.w;
        *(half8*)(d + (size_t)i*8) = h;
    }
}

// ---------------- generic NT GEMM: C[m,n] = sum_k A[m,k]*B[n,k] + bias ----------------
// BM=128 BN=128 BK=32, 256 threads (4 waves 2x2), fp16 MFMA 16x16x32, fp16 out.
template<bool GATHER>
__global__ __launch_bounds__(256)
void gemm_nt(const half_t* __restrict__ A, const float* __restrict__ Atab,
             const int* __restrict__ gidx, const half_t* __restrict__ Bm,
             const float* __restrict__ bias0, const float* __restrict__ bias1,
             half_t* __restrict__ Cout, int M, int N, int K)
{
    __shared__ half8 As8[512];   // 128 x 32 half
    __shared__ half8 Bs8[512];
    half_t* As = (half_t*)As8;
    half_t* Bs = (half_t*)Bs8;

    const int tid  = threadIdx.x;
    const int lane = tid & 63, wid = tid >> 6;
    const int wm = wid >> 1, wn = wid & 1;
    const int ln = lane & 15, hi = lane >> 4;
    const int m0 = blockIdx.x * 128, n0 = blockIdx.y * 128;

    floatx4 acc[4][4] = {};
    const int kTiles = K >> 5;

    for (int kt = 0; kt < kTiles; ++kt) {
        if constexpr (GATHER) {
            int r = tid >> 1, q = tid & 1;
            int row = gidx[m0 + r];
            const float* src = Atab + (size_t)row * EMB + kt*32 + q*16;
            float4 f0 = *(const float4*)(src);
            float4 f1 = *(const float4*)(src + 4);
            float4 f2 = *(const float4*)(src + 8);
            float4 f3 = *(const float4*)(src + 12);
            half8 h0, h1;
            h0[0]=(_Float16)f0.x; h0[1]=(_Float16)f0.y; h0[2]=(_Float16)f0.z; h0[3]=(_Float16)f0.w;
            h0[4]=(_Float16)f1.x; h0[5]=(_Float16)f1.y; h0[6]=(_Float16)f1.z; h0[7]=(_Float16)f1.w;
            h1[0]=(_Float16)f2.x; h1[1]=(_Float16)f2.y; h1[2]=(_Float16)f2.z; h1[3]=(_Float16)f2.w;
            h1[4]=(_Float16)f3.x; h1[5]=(_Float16)f3.y; h1[6]=(_Float16)f3.z; h1[7]=(_Float16)f3.w;
            int c0 = 2*q, c1 = 2*q + 1;
            *(half8*)(As + r*32 + (((c0 + (r>>1)) & 3) * 8)) = h0;
            *(half8*)(As + r*32 + (((c1 + (r>>1)) & 3) * 8)) = h1;
        } else {
            #pragma unroll
            for (int ii = 0; ii < 2; ++ii) {
                int ch = tid + ii*256; int r = ch >> 2, c = ch & 3;
                half8 v = *(const half8*)(A + (size_t)(m0+r)*K + kt*32 + c*8);
                *(half8*)(As + r*32 + (((c + (r>>1)) & 3) * 8)) = v;
            }
        }
        #pragma unroll
        for (int ii = 0; ii < 2; ++ii) {
            int ch = tid + ii*256; int r = ch >> 2, c = ch & 3;
            half8 v = *(const half8*)(Bm + (size_t)(n0+r)*K + kt*32 + c*8);
            *(half8*)(Bs + r*32 + (((c + (r>>1)) & 3) * 8)) = v;
        }
        __syncthreads();

        half8 af[4], bf[4];
        #pragma unroll
        for (int mt = 0; mt < 4; ++mt) {
            int r = wm*64 + mt*16 + ln;
            af[mt] = *(const half8*)(As + r*32 + ((hi + (r>>1)) & 3) * 8);
        }
        #pragma unroll
        for (int nt = 0; nt < 4; ++nt) {
            int r = wn*64 + nt*16 + ln;
            bf[nt] = *(const half8*)(Bs + r*32 + ((hi + (r>>1)) & 3) * 8);
        }
        #pragma unroll
        for (int mt = 0; mt < 4; ++mt)
            #pragma unroll
            for (int nt = 0; nt < 4; ++nt)
                acc[mt][nt] = __builtin_amdgcn_mfma_f32_16x16x32_f16(af[mt], bf[nt], acc[mt][nt], 0, 0, 0);
        __syncthreads();
    }

    #pragma unroll
    for (int mt = 0; mt < 4; ++mt) {
        #pragma unroll
        for (int nt = 0; nt < 4; ++nt) {
            int n = n0 + wn*64 + nt*16 + ln;
            float bv = (bias0 ? bias0[n] : 0.f) + (bias1 ? bias1[n] : 0.f);
            #pragma unroll
            for (int r = 0; r < 4; ++r) {
                int m = m0 + wm*64 + mt*16 + hi*4 + r;
                Cout[(size_t)m*N + n] = (half_t)(acc[mt][nt][r] + bv);
            }
        }
    }
}

// ---------------- persistent bidirectional RNN layer (round 4) ----------------
// grid = 32 blocks x 256 thr. dir = bid>>4; j-slice = (bid&15)*32; wave w -> batches [16w,16w+16).
// D[j][b] = sum_k W[j][k] h[b][k]: A = W (LDS, padded stride 520), B = h.
// Sync is IN-BAND: h is relu output (sign bit 0); producer ORs tag=((step+1)>>1)&1 into every
// fp16 sign bit of the atomically-stored 8B chunk and stores relaxed/agent -- no drain, no flag.
// Consumer polls exactly its 32-chunk read set until all sign bits match tag=(step>>1)&1;
// on success data is already in registers (mask 0x7FFF and MFMA). 2 transits/step.
// Deadlock-safe: wave (w,*) can only run 1 step ahead of same-w waves; buffers reused at distance 2.
__global__ __launch_bounds__(256, 1)
void rnn_layer(const half_t* __restrict__ xp, half_t* __restrict__ outbuf,
               const float* __restrict__ whh, ull_t* __restrict__ hb)
{
    __shared__ half_t Wlds[32*520 + 8];   // 32 rows x (512+8 pad) fp16

    const int bid = blockIdx.x;
    const int dir = bid >> 4;
    const int j0  = (bid & 15) * 32;
    const int wid = threadIdx.x >> 6, lane = threadIdx.x & 63;
    const int ln = lane & 15, hi = lane >> 4;
    const int b0 = wid * 16;

    // stage W[j0..j0+32)[0..512) fp32->fp16 into LDS
    for (int idx = threadIdx.x; idx < 32*64; idx += 256) {
        int r = idx >> 6, c8 = idx & 63;
        const float* wp = whh + ((size_t)(dir*HID + j0 + r))*HID + c8*8;
        float4 f0 = *(const float4*)wp;
        float4 f1 = *(const float4*)(wp + 4);
        half8 h;
        h[0]=(_Float16)f0.x; h[1]=(_Float16)f0.y; h[2]=(_Float16)f0.z; h[3]=(_Float16)f0.w;
        h[4]=(_Float16)f1.x; h[5]=(_Float16)f1.y; h[6]=(_Float16)f1.z; h[7]=(_Float16)f1.w;
        *(half8*)(Wlds + r*520 + c8*8) = h;
    }
    __syncthreads();

    // h double buffers in ull units: [2 buf][8192 ull] per direction
    ull_t* hb_d = hb + (size_t)dir * 16384;

    // per-lane fixed offsets
    const int b   = b0 + ln;                       // batch row this lane reads/writes
    const int jb0 = j0 + hi*4;                     // j quad base, mt adds 16
    const int hrd = b*128 + hi*2;                  // ull idx base for B-frag reads (+kk*8)
    const int hwr = b*128 + (jb0 >> 2);            // ull idx base for h writes (+mt*4)

    // prefetch xp for step 0
    half4 xq[2];
    {
        int t0 = dir ? (SEQ-1) : 0;
        const half_t* xb = xp + ((size_t)(t0*BATCH + b))*(2*HID) + dir*HID + jb0;
        xq[0] = *(const half4*)(xb);
        xq[1] = *(const half4*)(xb + 16);
    }

    for (int step = 0; step < SEQ; ++step) {
        const int t = dir ? (SEQ-1 - step) : step;
        const ull_t* hc = hb_d + (size_t)(step & 1) * 8192;
        ull_t*       hn = hb_d + (size_t)((step+1) & 1) * 8192;
        const unsigned pm = (unsigned)((step >> 1) & 1) << 15;               // expected tag bit
        const ull_t tagw  = (((step + 1) >> 1) & 1) ? 0x8000800080008000ull : 0ull;

        // poll own read set until every chunk carries this step's tag
        ull_t ua[16], uc[16];
        for (;;) {
            #pragma unroll
            for (int kk = 0; kk < 16; ++kk) {
                const ull_t* p = hc + hrd + kk*8;
                ua[kk] = __hip_atomic_load(p,     __ATOMIC_RELAXED, __HIP_MEMORY_SCOPE_AGENT);
                uc[kk] = __hip_atomic_load(p + 1, __ATOMIC_RELAXED, __HIP_MEMORY_SCOPE_AGENT);
            }
            unsigned bad = 0;
            #pragma unroll
            for (int kk = 0; kk < 16; ++kk) {
                bad |= (((unsigned)ua[kk]) & 0x8000u) ^ pm;
                bad |= (((unsigned)uc[kk]) & 0x8000u) ^ pm;
            }
            if (__ballot(bad == 0) == ~0ull) break;
        }

        // strip tags -> B fragments
        half8 bf[16];
        #pragma unroll
        for (int kk = 0; kk < 16; ++kk) {
            struct U2 { ull_t a, c; } u2;
            u2.a = ua[kk] & 0x7FFF7FFF7FFF7FFFull;
            u2.c = uc[kk] & 0x7FFF7FFF7FFF7FFFull;
            bf[kk] = __builtin_bit_cast(half8, u2);
        }

        floatx4 acc0 = {0.f,0.f,0.f,0.f};
        floatx4 acc1 = {0.f,0.f,0.f,0.f};
        #pragma unroll
        for (int kk = 0; kk < 16; ++kk) {
            half8 a0 = *(const half8*)(Wlds + (     ln)*520 + kk*32 + hi*8);
            half8 a1 = *(const half8*)(Wlds + (16 + ln)*520 + kk*32 + hi*8);
            acc0 = __builtin_amdgcn_mfma_f32_16x16x32_f16(a0, bf[kk], acc0, 0, 0, 0);
            acc1 = __builtin_amdgcn_mfma_f32_16x16x32_f16(a1, bf[kk], acc1, 0, 0, 0);
        }

        // epilogue: v = relu(acc + xp); fire-and-forget tagged h store, then outbuf + prefetch
        half4 hv[2];
        #pragma unroll
        for (int mt = 0; mt < 2; ++mt) {
            floatx4 a = mt ? acc1 : acc0;
            #pragma unroll
            for (int r = 0; r < 4; ++r)
                hv[mt][r] = (_Float16)fmaxf(a[r] + (float)xq[mt][r], 0.f);
        }
        if (step + 1 < SEQ) {
            #pragma unroll
            for (int mt = 0; mt < 2; ++mt) {
                ull_t w = __builtin_bit_cast(ull_t, hv[mt]) | tagw;
                __hip_atomic_store(hn + hwr + mt*4, w,
                                   __ATOMIC_RELAXED, __HIP_MEMORY_SCOPE_AGENT);
            }
        }

        const size_t orow = ((size_t)t*BATCH + b)*(2*HID) + dir*HID;
        #pragma unroll
        for (int mt = 0; mt < 2; ++mt)
            *(half4*)(outbuf + orow + jb0 + mt*16) = hv[mt];

        if (step + 1 < SEQ) {
            int tn = dir ? (SEQ-2 - step) : (step+1);
            const half_t* xb = xp + ((size_t)(tn*BATCH + b))*(2*HID) + dir*HID + jb0;
            xq[0] = *(const half4*)(xb);
            xq[1] = *(const half4*)(xb + 16);
        }
    }
}

// ---------------- final FC: [16384,1024] x [18,1024]^T + b ----------------
__global__ __launch_bounds__(256)
void fc_kernel(const half_t* __restrict__ X, const half_t* __restrict__ W16,
               const float* __restrict__ bias, float* __restrict__ Y)
{
    __shared__ half8 Ws8[2304];   // 18*1024 half
    half_t* Ws = (half_t*)Ws8;
    for (int ch = threadIdx.x; ch < 2304; ch += 256)
        Ws8[ch] = *(const half8*)(W16 + (size_t)ch*8);
    __syncthreads();

    int wi = threadIdx.x >> 6, lane = threadIdx.x & 63;
    int m = blockIdx.x*4 + wi;
    const half_t* xr = X + (size_t)m*1024 + lane*16;
    half8 x0 = *(const half8*)xr;
    half8 x1 = *(const half8*)(xr + 8);
    float xa[16];
    #pragma unroll
    for (int i = 0; i < 8; ++i) { xa[i] = (float)x0[i]; xa[8+i] = (float)x1[i]; }

    for (int n = 0; n < NOUT; ++n) {
        const half_t* wr = Ws + n*1024 + lane*16;
        half8 w0 = *(const half8*)wr;
        half8 w1 = *(const half8*)(wr + 8);
        float s = 0.f;
        #pragma unroll
        for (int i = 0; i < 8; ++i) s += xa[i]*(float)w0[i] + xa[8+i]*(float)w1[i];
        #pragma unroll
        for (int off = 32; off > 0; off >>= 1) s += __shfl_down(s, off, 64);
        if (lane == 0) Y[(size_t)m*NOUT + n] = s + bias[n];
    }
}

// ---------------- launcher ----------------
extern "C" void kernel_launch(void* const* d_in, const int* in_sizes, int n_in,
                              void* d_out, int out_size, void* d_ws, size_t ws_size,
                              hipStream_t stream)
{
    const int*   text    = (const int*)  d_in[0];
    const float* emb     = (const float*)d_in[1];
    const float* emfc_w  = (const float*)d_in[2];
    const float* emfc_b  = (const float*)d_in[3];
    const float* w_ih0   = (const float*)d_in[4];
    const float* w_hh0   = (const float*)d_in[5];
    const float* b_ih0   = (const float*)d_in[6];
    const float* b_hh0   = (const float*)d_in[7];
    const float* w_ih1   = (const float*)d_in[8];
    const float* w_hh1   = (const float*)d_in[9];
    const float* b_ih1   = (const float*)d_in[10];
    const float* b_hh1   = (const float*)d_in[11];
    const float* fc_w    = (const float*)d_in[12];
    const float* fc_b    = (const float*)d_in[13];
    float* out = (float*)d_out;

    char* ws = (char*)d_ws;
    ull_t*  hb0    = (ull_t*) (ws + O_HB0);
    ull_t*  hb1    = (ull_t*) (ws + O_HB1);
    half_t* emfc16 = (half_t*)(ws + O_EMFC16);
    half_t* wih0   = (half_t*)(ws + O_WIH0);
    half_t* wih1   = (half_t*)(ws + O_WIH1);
    half_t* fc16   = (half_t*)(ws + O_FC16);
    half_t* pe     = (half_t*)(ws + O_PE);
    half_t* xp     = (half_t*)(ws + O_XP);
    half_t* out0   = (half_t*)(ws + O_OUT0);
    half_t* out1   = (half_t*)(ws + O_OUT1);

    // 1) init h buffers (both layers, both dirs): buf0 = 0 (valid h_0), buf1 = 0x8000 (stale tag)
    init_hb<<<128, 256, 0, stream>>>((uint4*)ws);

    // 2) weight conversions fp32->fp16
    cvt_f32f16<<<32,  256, 0, stream>>>(emfc_w, emfc16, 8192);
    cvt_f32f16<<<128, 256, 0, stream>>>(w_ih0,  wih0,  32768);
    cvt_f32f16<<<512, 256, 0, stream>>>(w_ih1,  wih1, 131072);
    cvt_f32f16<<<9,   256, 0, stream>>>(fc_w,   fc16,   2304);

    // 3) post_emb = gather(emb, text) @ emfc_w^T + emfc_b   (PE aliases OUT1 region)
    gemm_nt<true><<<dim3(M_TOT/128, EMB/128), 256, 0, stream>>>(
        nullptr, emb, text, emfc16, emfc_b, nullptr, pe, M_TOT, EMB, EMB);

    // 4) xp0 = post_emb @ w_ih0^T + (b_ih0 + b_hh0)
    gemm_nt<false><<<dim3(M_TOT/128, (2*HID)/128), 256, 0, stream>>>(
        pe, nullptr, nullptr, wih0, b_ih0, b_hh0, xp, M_TOT, 2*HID, EMB);

    // 5) layer0 recurrence (both directions)
    rnn_layer<<<32, 256, 0, stream>>>(xp, out0, w_hh0, hb0);

    // 6) xp1 = out0 @ w_ih1^T + (b_ih1 + b_hh1)
    gemm_nt<false><<<dim3(M_TOT/128, (2*HID)/128), 256, 0, stream>>>(
        out0, nullptr, nullptr, wih1, b_ih1, b_hh1, xp, M_TOT, 2*HID, 2*HID);

    // 7) layer1 recurrence
    rnn_layer<<<32, 256, 0, stream>>>(xp, out1, w_hh1, hb1);

    // 8) out = out1 @ fc_w^T + fc_b
    fc_kernel<<<M_TOT/4, 256, 0, stream>>>(out1, fc16, fc_b, out);
}

// Round 6
// 3572.344 us; speedup vs baseline: 1.1784x; 1.1218x over previous
//
#include <hip/hip_runtime.h>

typedef _Float16 half_t;
typedef _Float16 half4 __attribute__((ext_vector_type(4)));
typedef _Float16 half8 __attribute__((ext_vector_type(8)));
typedef float floatx4 __attribute__((ext_vector_type(4)));
typedef unsigned long long ull_t;

#define SEQ 256
#define BATCH 64
#define EMB 256
#define HID 512
#define NOUT 18
#define M_TOT (SEQ*BATCH)   // 16384

// ---------------- ws layout (bytes) ----------------
#define O_CNT    0u          // 4 counters (2 layer x 2 dir), 128B apart (512B)
#define O_HB0    512u        // layer0 h double buffers [2 dir][2 buf][64 b][512 j] fp16 = 262144
#define O_HB1    262656u     // layer1 same
#define O_EMFC16 524800u     // 65536 half = 131072
#define O_WIH0   655872u     // 1024*256 half = 524288
#define O_WIH1   1180160u    // 1024*1024 half = 2097152
#define O_FC16   3277312u    // 18*1024 half = 36864 (pad)
#define O_XP     3314176u    // 16384*1024 half = 33554432 (shared by layer0/layer1)
#define O_OUT0   36868608u   // 16384*1024 half
#define O_OUT1   70423040u   // 16384*1024 half
#define O_PE     O_OUT1      // post_emb 16384*256 half ALIASES OUT1 (PE dead before OUT1 written)
// total 103977472 bytes

// ---------------- zero helper ----------------
__global__ void zero_ws(uint4* p, int n) {
    int i = blockIdx.x * 256 + threadIdx.x;
    if (i < n) p[i] = make_uint4(0u, 0u, 0u, 0u);
}

// ---------------- fp32 -> fp16 convert (8 elems/thread) ----------------
__global__ void cvt_f32f16(const float* __restrict__ s, half_t* __restrict__ d, int n8) {
    int i = blockIdx.x * 256 + threadIdx.x;
    if (i < n8) {
        const float4* s4 = (const float4*)s;
        float4 a = s4[2*i], b = s4[2*i+1];
        half8 h;
        h[0]=(_Float16)a.x; h[1]=(_Float16)a.y; h[2]=(_Float16)a.z; h[3]=(_Float16)a.w;
        h[4]=(_Float16)b.x; h[5]=(_Float16)b.y; h[6]=(_Float16)b.z; h[7]=(_Float16)b.w;
        *(half8*)(d + (size_t)i*8) = h;
    }
}

// ---------------- generic NT GEMM: C[m,n] = sum_k A[m,k]*B[n,k] + bias ----------------
// BM=128 BN=128 BK=32, 256 threads (4 waves 2x2), fp16 MFMA 16x16x32, fp16 out.
template<bool GATHER>
__global__ __launch_bounds__(256)
void gemm_nt(const half_t* __restrict__ A, const float* __restrict__ Atab,
             const int* __restrict__ gidx, const half_t* __restrict__ Bm,
             const float* __restrict__ bias0, const float* __restrict__ bias1,
             half_t* __restrict__ Cout, int M, int N, int K)
{
    __shared__ half8 As8[512];   // 128 x 32 half
    __shared__ half8 Bs8[512];
    half_t* As = (half_t*)As8;
    half_t* Bs = (half_t*)Bs8;

    const int tid  = threadIdx.x;
    const int lane = tid & 63, wid = tid >> 6;
    const int wm = wid >> 1, wn = wid & 1;
    const int ln = lane & 15, hi = lane >> 4;
    const int m0 = blockIdx.x * 128, n0 = blockIdx.y * 128;

    floatx4 acc[4][4] = {};
    const int kTiles = K >> 5;

    for (int kt = 0; kt < kTiles; ++kt) {
        if constexpr (GATHER) {
            int r = tid >> 1, q = tid & 1;
            int row = gidx[m0 + r];
            const float* src = Atab + (size_t)row * EMB + kt*32 + q*16;
            float4 f0 = *(const float4*)(src);
            float4 f1 = *(const float4*)(src + 4);
            float4 f2 = *(const float4*)(src + 8);
            float4 f3 = *(const float4*)(src + 12);
            half8 h0, h1;
            h0[0]=(_Float16)f0.x; h0[1]=(_Float16)f0.y; h0[2]=(_Float16)f0.z; h0[3]=(_Float16)f0.w;
            h0[4]=(_Float16)f1.x; h0[5]=(_Float16)f1.y; h0[6]=(_Float16)f1.z; h0[7]=(_Float16)f1.w;
            h1[0]=(_Float16)f2.x; h1[1]=(_Float16)f2.y; h1[2]=(_Float16)f2.z; h1[3]=(_Float16)f2.w;
            h1[4]=(_Float16)f3.x; h1[5]=(_Float16)f3.y; h1[6]=(_Float16)f3.z; h1[7]=(_Float16)f3.w;
            int c0 = 2*q, c1 = 2*q + 1;
            *(half8*)(As + r*32 + (((c0 + (r>>1)) & 3) * 8)) = h0;
            *(half8*)(As + r*32 + (((c1 + (r>>1)) & 3) * 8)) = h1;
        } else {
            #pragma unroll
            for (int ii = 0; ii < 2; ++ii) {
                int ch = tid + ii*256; int r = ch >> 2, c = ch & 3;
                half8 v = *(const half8*)(A + (size_t)(m0+r)*K + kt*32 + c*8);
                *(half8*)(As + r*32 + (((c + (r>>1)) & 3) * 8)) = v;
            }
        }
        #pragma unroll
        for (int ii = 0; ii < 2; ++ii) {
            int ch = tid + ii*256; int r = ch >> 2, c = ch & 3;
            half8 v = *(const half8*)(Bm + (size_t)(n0+r)*K + kt*32 + c*8);
            *(half8*)(Bs + r*32 + (((c + (r>>1)) & 3) * 8)) = v;
        }
        __syncthreads();

        half8 af[4], bf[4];
        #pragma unroll
        for (int mt = 0; mt < 4; ++mt) {
            int r = wm*64 + mt*16 + ln;
            af[mt] = *(const half8*)(As + r*32 + ((hi + (r>>1)) & 3) * 8);
        }
        #pragma unroll
        for (int nt = 0; nt < 4; ++nt) {
            int r = wn*64 + nt*16 + ln;
            bf[nt] = *(const half8*)(Bs + r*32 + ((hi + (r>>1)) & 3) * 8);
        }
        #pragma unroll
        for (int mt = 0; mt < 4; ++mt)
            #pragma unroll
            for (int nt = 0; nt < 4; ++nt)
                acc[mt][nt] = __builtin_amdgcn_mfma_f32_16x16x32_f16(af[mt], bf[nt], acc[mt][nt], 0, 0, 0);
        __syncthreads();
    }

    #pragma unroll
    for (int mt = 0; mt < 4; ++mt) {
        #pragma unroll
        for (int nt = 0; nt < 4; ++nt) {
            int n = n0 + wn*64 + nt*16 + ln;
            float bv = (bias0 ? bias0[n] : 0.f) + (bias1 ? bias1[n] : 0.f);
            #pragma unroll
            for (int r = 0; r < 4; ++r) {
                int m = m0 + wm*64 + mt*16 + hi*4 + r;
                Cout[(size_t)m*N + n] = (half_t)(acc[mt][nt][r] + bv);
            }
        }
    }
}

// ---------------- persistent bidirectional RNN layer (round 6 = round 5 + hwr fix) ----------------
// 16 blocks x 256 thr. dir = (p>>2)&1; j-slice = 64 wide; wave w -> batches [16w,16w+16).
// D[j][b] = W[j][k] h[b][k]: A = W (LDS, fragment-major, conflict-free), B = h.
// h exchange: producer = uncached 8B atomic stores -> vmcnt(0) -> per-wave counter add (relaxed).
// consumer = poll counter (1 uncached load/wave/iter) -> ONE acquire fence (buffer_inv, no wb)
// -> normal CACHED 16B loads of h. L2 absorbs the 16x broadcast amplification per XCD.
// h buffer is [64 b][512 j] fp16 = 128 ull per batch row: ull index = b*128 + j/4.
__global__ __launch_bounds__(256, 1)
void rnn_layer(const half_t* __restrict__ xp, half_t* __restrict__ outbuf,
               const float* __restrict__ whh, ull_t* __restrict__ hb,
               int* __restrict__ cnt)
{
    __shared__ half8 Wf[4][16][64];   // 64 KB, fragment-major: Wf[mt][kk][lane]

    const int p    = blockIdx.x;
    const int dir  = (p >> 2) & 1;
    const int sidx = (p & 3) | ((p >> 3) << 2);
    const int j0   = sidx * 64;
    const int lane = threadIdx.x & 63, wid = threadIdx.x >> 6;
    const int ln   = lane & 15, hi = lane >> 4;
    const int b    = wid * 16 + ln;

    // stage W fragments: Wf[mt][kk][l] = W[dir*HID + j0 + mt*16 + (l&15)][kk*32 + (l>>4)*8 ..+8]
    for (int idx = threadIdx.x; idx < 4096; idx += 256) {
        int l = idx & 63, kk = (idx >> 6) & 15, mt = idx >> 10;
        const float* wp = whh + ((size_t)(dir*HID + j0 + mt*16 + (l & 15)))*HID
                               + kk*32 + (l >> 4)*8;
        float4 f0 = *(const float4*)wp;
        float4 f1 = *(const float4*)(wp + 4);
        half8 h;
        h[0]=(_Float16)f0.x; h[1]=(_Float16)f0.y; h[2]=(_Float16)f0.z; h[3]=(_Float16)f0.w;
        h[4]=(_Float16)f1.x; h[5]=(_Float16)f1.y; h[6]=(_Float16)f1.z; h[7]=(_Float16)f1.w;
        Wf[mt][kk][l] = h;
    }
    __syncthreads();

    ull_t* hb_d = hb + (size_t)dir * 16384;   // [2 buf][8192 ull]
    int*   cp   = cnt + dir * 32;             // 128 B apart per dir

    const int hwr = b*128 + (j0 >> 2) + hi;   // ull idx for h writes, +mt*4   [FIXED: was b*64]

    // prefetch xp for step 0
    half4 xq[4];
    {
        int t0 = dir ? (SEQ-1) : 0;
        const half_t* xb = xp + ((size_t)(t0*BATCH + b))*(2*HID) + dir*HID + j0 + hi*4;
        #pragma unroll
        for (int mt = 0; mt < 4; ++mt) xq[mt] = *(const half4*)(xb + mt*16);
    }

    for (int step = 0; step < SEQ; ++step) {
        const int t = dir ? (SEQ-1 - step) : step;
        const half_t* hc = (const half_t*)(hb_d + (size_t)(step & 1) * 8192);
        ull_t*        hn = hb_d + (size_t)((step+1) & 1) * 8192;

        if (step) {
            const int tgt = 32 * step;
            while (__hip_atomic_load(cp, __ATOMIC_RELAXED, __HIP_MEMORY_SCOPE_AGENT) < tgt) {}
            __builtin_amdgcn_fence(__ATOMIC_ACQUIRE, "agent");   // buffer_inv: drop stale L2 lines
        }

        // B-operand (h): CACHED 16B loads; wave reads h[b][0..512)
        half8 bf[16];
        #pragma unroll
        for (int kk = 0; kk < 16; ++kk)
            bf[kk] = *(const half8*)(hc + b*512 + kk*32 + hi*8);

        floatx4 acc[4] = {{0.f,0.f,0.f,0.f},{0.f,0.f,0.f,0.f},{0.f,0.f,0.f,0.f},{0.f,0.f,0.f,0.f}};
        #pragma unroll
        for (int kk = 0; kk < 16; ++kk) {
            #pragma unroll
            for (int mt = 0; mt < 4; ++mt)
                acc[mt] = __builtin_amdgcn_mfma_f32_16x16x32_f16(Wf[mt][kk][lane], bf[kk], acc[mt], 0, 0, 0);
        }

        // epilogue: v = relu(acc + xp); lane holds j quad j0+mt*16+hi*4 for batch b
        half4 hv[4];
        #pragma unroll
        for (int mt = 0; mt < 4; ++mt) {
            #pragma unroll
            for (int r = 0; r < 4; ++r)
                hv[mt][r] = (_Float16)fmaxf(acc[mt][r] + (float)xq[mt][r], 0.f);
        }

        if (step + 1 < SEQ) {
            #pragma unroll
            for (int mt = 0; mt < 4; ++mt)
                __hip_atomic_store(hn + hwr + mt*4, __builtin_bit_cast(ull_t, hv[mt]),
                                   __ATOMIC_RELAXED, __HIP_MEMORY_SCOPE_AGENT);
            asm volatile("s_waitcnt vmcnt(0)" ::: "memory");   // h stores at coherence point
            if (lane == 0)
                __hip_atomic_fetch_add(cp, 1, __ATOMIC_RELAXED, __HIP_MEMORY_SCOPE_AGENT);
        }

        // off critical path: cached outbuf store + next-step xp prefetch
        const size_t orow = ((size_t)t*BATCH + b)*(2*HID) + dir*HID + j0 + hi*4;
        #pragma unroll
        for (int mt = 0; mt < 4; ++mt)
            *(half4*)(outbuf + orow + mt*16) = hv[mt];

        if (step + 1 < SEQ) {
            int tn = dir ? (SEQ-2 - step) : (step+1);
            const half_t* xb = xp + ((size_t)(tn*BATCH + b))*(2*HID) + dir*HID + j0 + hi*4;
            #pragma unroll
            for (int mt = 0; mt < 4; ++mt) xq[mt] = *(const half4*)(xb + mt*16);
        }
    }
}

// ---------------- final FC: [16384,1024] x [18,1024]^T + b ----------------
__global__ __launch_bounds__(256)
void fc_kernel(const half_t* __restrict__ X, const half_t* __restrict__ W16,
               const float* __restrict__ bias, float* __restrict__ Y)
{
    __shared__ half8 Ws8[2304];   // 18*1024 half
    half_t* Ws = (half_t*)Ws8;
    for (int ch = threadIdx.x; ch < 2304; ch += 256)
        Ws8[ch] = *(const half8*)(W16 + (size_t)ch*8);
    __syncthreads();

    int wi = threadIdx.x >> 6, lane = threadIdx.x & 63;
    int m = blockIdx.x*4 + wi;
    const half_t* xr = X + (size_t)m*1024 + lane*16;
    half8 x0 = *(const half8*)xr;
    half8 x1 = *(const half8*)(xr + 8);
    float xa[16];
    #pragma unroll
    for (int i = 0; i < 8; ++i) { xa[i] = (float)x0[i]; xa[8+i] = (float)x1[i]; }

    for (int n = 0; n < NOUT; ++n) {
        const half_t* wr = Ws + n*1024 + lane*16;
        half8 w0 = *(const half8*)wr;
        half8 w1 = *(const half8*)(wr + 8);
        float s = 0.f;
        #pragma unroll
        for (int i = 0; i < 8; ++i) s += xa[i]*(float)w0[i] + xa[8+i]*(float)w1[i];
        #pragma unroll
        for (int off = 32; off > 0; off >>= 1) s += __shfl_down(s, off, 64);
        if (lane == 0) Y[(size_t)m*NOUT + n] = s + bias[n];
    }
}

// ---------------- launcher ----------------
extern "C" void kernel_launch(void* const* d_in, const int* in_sizes, int n_in,
                              void* d_out, int out_size, void* d_ws, size_t ws_size,
                              hipStream_t stream)
{
    const int*   text    = (const int*)  d_in[0];
    const float* emb     = (const float*)d_in[1];
    const float* emfc_w  = (const float*)d_in[2];
    const float* emfc_b  = (const float*)d_in[3];
    const float* w_ih0   = (const float*)d_in[4];
    const float* w_hh0   = (const float*)d_in[5];
    const float* b_ih0   = (const float*)d_in[6];
    const float* b_hh0   = (const float*)d_in[7];
    const float* w_ih1   = (const float*)d_in[8];
    const float* w_hh1   = (const float*)d_in[9];
    const float* b_ih1   = (const float*)d_in[10];
    const float* b_hh1   = (const float*)d_in[11];
    const float* fc_w    = (const float*)d_in[12];
    const float* fc_b    = (const float*)d_in[13];
    float* out = (float*)d_out;

    char* ws = (char*)d_ws;
    int*    cnt    = (int*)   (ws + O_CNT);
    ull_t*  hb0    = (ull_t*) (ws + O_HB0);
    ull_t*  hb1    = (ull_t*) (ws + O_HB1);
    half_t* emfc16 = (half_t*)(ws + O_EMFC16);
    half_t* wih0   = (half_t*)(ws + O_WIH0);
    half_t* wih1   = (half_t*)(ws + O_WIH1);
    half_t* fc16   = (half_t*)(ws + O_FC16);
    half_t* pe     = (half_t*)(ws + O_PE);
    half_t* xp     = (half_t*)(ws + O_XP);
    half_t* out0   = (half_t*)(ws + O_OUT0);
    half_t* out1   = (half_t*)(ws + O_OUT1);

    // 1) zero counters + all h buffers ([0, 524800) = 32800 uint4)
    zero_ws<<<129, 256, 0, stream>>>((uint4*)ws, 32800);

    // 2) weight conversions fp32->fp16
    cvt_f32f16<<<32,  256, 0, stream>>>(emfc_w, emfc16, 8192);
    cvt_f32f16<<<128, 256, 0, stream>>>(w_ih0,  wih0,  32768);
    cvt_f32f16<<<512, 256, 0, stream>>>(w_ih1,  wih1, 131072);
    cvt_f32f16<<<9,   256, 0, stream>>>(fc_w,   fc16,   2304);

    // 3) post_emb = gather(emb, text) @ emfc_w^T + emfc_b   (PE aliases OUT1 region)
    gemm_nt<true><<<dim3(M_TOT/128, EMB/128), 256, 0, stream>>>(
        nullptr, emb, text, emfc16, emfc_b, nullptr, pe, M_TOT, EMB, EMB);

    // 4) xp0 = post_emb @ w_ih0^T + (b_ih0 + b_hh0)
    gemm_nt<false><<<dim3(M_TOT/128, (2*HID)/128), 256, 0, stream>>>(
        pe, nullptr, nullptr, wih0, b_ih0, b_hh0, xp, M_TOT, 2*HID, EMB);

    // 5) layer0 recurrence (both directions), counters at cnt[0..63]
    rnn_layer<<<16, 256, 0, stream>>>(xp, out0, w_hh0, hb0, cnt);

    // 6) xp1 = out0 @ w_ih1^T + (b_ih1 + b_hh1)
    gemm_nt<false><<<dim3(M_TOT/128, (2*HID)/128), 256, 0, stream>>>(
        out0, nullptr, nullptr, wih1, b_ih1, b_hh1, xp, M_TOT, 2*HID, 2*HID);

    // 7) layer1 recurrence, counters at cnt[64..127]
    rnn_layer<<<16, 256, 0, stream>>>(xp, out1, w_hh1, hb1, cnt + 64);

    // 8) out = out1 @ fc_w^T + fc_b
    fc_kernel<<<M_TOT/4, 256, 0, stream>>>(out1, fc16, fc_b, out);
}